// Round 2
// baseline (283.420 us; speedup 1.0000x reference)
//
#include <hip/hip_runtime.h>
#include <hip/hip_bf16.h>

#define BATCH 2048
#define IN_DIM 512
#define HID 1024
#define NE 16
#define EPSV 1e-5f

typedef __bf16 bf16x8 __attribute__((ext_vector_type(8)));
typedef float floatx4 __attribute__((ext_vector_type(4)));
typedef unsigned short ushort8 __attribute__((ext_vector_type(8)));

__device__ __forceinline__ unsigned short f2bf(float f) {
  unsigned int u = __builtin_bit_cast(unsigned int, f);
  u += 0x7FFFu + ((u >> 16) & 1u);   // RNE
  return (unsigned short)(u >> 16);
}

// Harness converts integer inputs to int32 ("integer -> const int*"), but be
// robust to an int64 passthrough: for int64 arange the odd int32 words are 0.
__device__ __forceinline__ int get_expert(const int* __restrict__ idx, int e) {
  bool is64 = (idx[1] == 0) && (idx[3] == 0);
  return is64 ? (int)((const long long*)idx)[e] : idx[e];
}

// ---------------- prep 1: BN coefficients (gathered by expert_indices) -------
__global__ __launch_bounds__(256) void prep_coef(
    const int* __restrict__ idx, const float* __restrict__ bnw,
    const float* __restrict__ bnb, const float* __restrict__ rmean,
    const float* __restrict__ rvar, const float* __restrict__ ebias,
    float* __restrict__ Ac, float* __restrict__ Cc) {
  int t = blockIdx.x * 256 + threadIdx.x;      // 16384 = NE*HID
  int e = t >> 10, h = t & 1023;
  int ie = get_expert(idx, e);
  size_t o = (size_t)ie * HID + h;
  float scale = bnw[o] * rsqrtf(rvar[o] + EPSV);
  Ac[t] = scale;
  Cc[t] = (ebias[o] - rmean[o]) * scale + bnb[o];
}

// ---------------- prep 2: LoRA gate (xg bf16) + softmax gate g ---------------
__global__ __launch_bounds__(256) void prep_rows(
    const float* __restrict__ x, const float* __restrict__ gs,
    const float* __restrict__ gw, const float* __restrict__ lA,
    const float* __restrict__ lB,
    unsigned short* __restrict__ xg, float* __restrict__ g) {
  int lane = threadIdx.x & 63;
  int wid = threadIdx.x >> 6;
  int b = blockIdx.x * 4 + wid;                // one wave per row
  const float* xrow = x + (size_t)b * IN_DIM;
  const float* grow = gs + (size_t)b * IN_DIM;
  int d0 = lane * 8;

  float4 xa = *(const float4*)(xrow + d0);
  float4 xb = *(const float4*)(xrow + d0 + 4);
  float xv[8] = {xa.x, xa.y, xa.z, xa.w, xb.x, xb.y, xb.z, xb.w};
  float4 ga = *(const float4*)(grow + d0);
  float4 gb = *(const float4*)(grow + d0 + 4);
  float gv[8] = {ga.x, ga.y, ga.z, ga.w, gb.x, gb.y, gb.z, gb.w};

  // LoRA u = x @ A  (rank 2)
  float u0 = 0.f, u1 = 0.f;
#pragma unroll
  for (int j = 0; j < 8; ++j) {
    float2 a2 = *(const float2*)(lA + (size_t)(d0 + j) * 2);
    u0 += xv[j] * a2.x;
    u1 += xv[j] * a2.y;
  }
#pragma unroll
  for (int off = 1; off < 64; off <<= 1) {
    u0 += __shfl_xor(u0, off);
    u1 += __shfl_xor(u1, off);
  }

  // gate logits
  float ge[16];
#pragma unroll
  for (int e = 0; e < 16; ++e) ge[e] = 0.f;
#pragma unroll
  for (int j = 0; j < 8; ++j) {
    float q = gv[j];
    const float4* gwr = (const float4*)(gw + (size_t)(d0 + j) * NE);
    float4 w0 = gwr[0], w1 = gwr[1], w2 = gwr[2], w3 = gwr[3];
    ge[0] += q * w0.x; ge[1] += q * w0.y; ge[2] += q * w0.z; ge[3] += q * w0.w;
    ge[4] += q * w1.x; ge[5] += q * w1.y; ge[6] += q * w1.z; ge[7] += q * w1.w;
    ge[8] += q * w2.x; ge[9] += q * w2.y; ge[10] += q * w2.z; ge[11] += q * w2.w;
    ge[12] += q * w3.x; ge[13] += q * w3.y; ge[14] += q * w3.z; ge[15] += q * w3.w;
  }
#pragma unroll
  for (int off = 1; off < 64; off <<= 1) {
#pragma unroll
    for (int e = 0; e < 16; ++e) ge[e] += __shfl_xor(ge[e], off);
  }
  float m = ge[0];
#pragma unroll
  for (int e = 1; e < 16; ++e) m = fmaxf(m, ge[e]);
  float p[16], s = 0.f;
#pragma unroll
  for (int e = 0; e < 16; ++e) { p[e] = __expf(ge[e] - m); s += p[e]; }
  float inv = 1.f / s;
  if (lane == 0) {
    float* gout = g + (size_t)b * NE;
#pragma unroll
    for (int e = 0; e < 16; ++e) gout[e] = p[e] * inv;
  }

  // xg = x * sigmoid(u @ B) -> bf16
  ushort8 ov;
#pragma unroll
  for (int j = 0; j < 8; ++j) {
    float t = u0 * lB[d0 + j] + u1 * lB[IN_DIM + d0 + j];
    float sg = 1.f / (1.f + __expf(-t));
    ov[j] = f2bf(xv[j] * sg);
  }
  *(ushort8*)(xg + (size_t)b * IN_DIM + d0) = ov;
}

// ---------------- prep 3: W[e][k][h] fp32 -> WbfT[e][h][k] bf16 --------------
__global__ __launch_bounds__(256) void prep_tw(
    const int* __restrict__ idx, const float* __restrict__ W,
    unsigned short* __restrict__ WT) {
  int bid = blockIdx.x;                // 16 * 8 * 16 = 2048 blocks
  int e = bid >> 7;
  int kt = (bid >> 4) & 7;
  int ht = bid & 15;
  int ie = get_expert(idx, e);
  int k0 = kt * 64, h0 = ht * 64;
  __shared__ float tile[64][65];
  const float* Wp = W + (size_t)ie * IN_DIM * HID;
#pragma unroll
  for (int i = 0; i < 4; ++i) {
    int id = threadIdx.x + i * 256;    // 0..1023
    int k = id >> 4, c = (id & 15) * 4;
    float4 v = *(const float4*)(Wp + (size_t)(k0 + k) * HID + h0 + c);
    tile[k][c] = v.x; tile[k][c + 1] = v.y; tile[k][c + 2] = v.z; tile[k][c + 3] = v.w;
  }
  __syncthreads();
#pragma unroll
  for (int i = 0; i < 2; ++i) {
    int id = threadIdx.x + i * 256;    // 0..511
    int h = id >> 3, kc = (id & 7) * 8;
    ushort8 o;
#pragma unroll
    for (int j = 0; j < 8; ++j) o[j] = f2bf(tile[kc + j][h]);
    *(ushort8*)(WT + ((size_t)e * HID + h0 + h) * IN_DIM + k0 + kc) = o;
  }
}

// ---------------- main: fused 16-expert GEMM + BN/SiLU + gated combine -------
#define BM 64
#define BN 128
#define BK 64
#define AST 72   // LDS row stride (ushorts): 144B, 16B aligned, 2-way banks (free)
#define BST 72

__global__ __launch_bounds__(256) void moe_main(
    const unsigned short* __restrict__ xg, const unsigned short* __restrict__ WT,
    const float* __restrict__ g, const float* __restrict__ Ac,
    const float* __restrict__ Cc, float* __restrict__ out) {
  __shared__ __align__(16) unsigned short As[2][BM * AST];
  __shared__ __align__(16) unsigned short Bs[2][BN * BST];
  __shared__ float gS[BM * 17];

  int tid = threadIdx.x;
  int lane = tid & 63, wid = tid >> 6;
  int wr = wid >> 1, wc = wid & 1;     // wave tile: rows wr*32.., cols wc*64..
  int l15 = lane & 15, quad = lane >> 4;

  int bid = blockIdx.x;
  int colb = bid & 7, rowb = bid >> 3; // col-block == XCD slot for L2 reuse
  int row0 = rowb * BM, col0 = colb * BN;

  for (int i = tid; i < BM * NE; i += 256) {
    int r = i >> 4, e = i & 15;
    gS[r * 17 + e] = g[(size_t)(row0 + r) * NE + e];
  }

  uint4 pA[2], pB[4];
  auto loadT = [&](int t) {
    int e = t >> 3, s = t & 7, k0 = s * BK;
#pragma unroll
    for (int j = 0; j < 2; ++j) {
      int id = tid + j * 256;          // 0..511
      int r = id >> 3, kc = (id & 7) * 8;
      pA[j] = *(const uint4*)(xg + (size_t)(row0 + r) * IN_DIM + k0 + kc);
    }
    const unsigned short* Wb = WT + ((size_t)e * HID + col0) * IN_DIM + k0;
#pragma unroll
    for (int j = 0; j < 4; ++j) {
      int id = tid + j * 256;          // 0..1023
      int c = id >> 3, kc = (id & 7) * 8;
      pB[j] = *(const uint4*)(Wb + (size_t)c * IN_DIM + kc);
    }
  };
  auto writeT = [&](int buf) {
#pragma unroll
    for (int j = 0; j < 2; ++j) {
      int id = tid + j * 256;
      int r = id >> 3, kc = (id & 7) * 8;
      *(uint4*)&As[buf][r * AST + kc] = pA[j];
    }
#pragma unroll
    for (int j = 0; j < 4; ++j) {
      int id = tid + j * 256;
      int c = id >> 3, kc = (id & 7) * 8;
      *(uint4*)&Bs[buf][c * BST + kc] = pB[j];
    }
  };

  floatx4 acc[2][4], oacc[2][4];
#pragma unroll
  for (int rt = 0; rt < 2; ++rt)
#pragma unroll
    for (int ct = 0; ct < 4; ++ct)
#pragma unroll
      for (int r = 0; r < 4; ++r) { acc[rt][ct][r] = 0.f; oacc[rt][ct][r] = 0.f; }

  loadT(0);
  writeT(0);
  __syncthreads();
  int buf = 0;
  for (int t = 0; t < NE * 8; ++t) {
    int s = t & 7;
    if (t < NE * 8 - 1) loadT(t + 1);
#pragma unroll
    for (int kk = 0; kk < 2; ++kk) {
      bf16x8 af[2], bfr[4];
#pragma unroll
      for (int rt = 0; rt < 2; ++rt)
        af[rt] = *(const bf16x8*)&As[buf][(wr * 32 + rt * 16 + l15) * AST + kk * 32 + quad * 8];
#pragma unroll
      for (int ct = 0; ct < 4; ++ct)
        bfr[ct] = *(const bf16x8*)&Bs[buf][(wc * 64 + ct * 16 + l15) * BST + kk * 32 + quad * 8];
#pragma unroll
      for (int rt = 0; rt < 2; ++rt)
#pragma unroll
        for (int ct = 0; ct < 4; ++ct)
          acc[rt][ct] = __builtin_amdgcn_mfma_f32_16x16x32_bf16(af[rt], bfr[ct], acc[rt][ct], 0, 0, 0);
    }
    if (s == 7) {                       // expert epilogue: BN + SiLU + gated acc
      int e = t >> 3;
#pragma unroll
      for (int ct = 0; ct < 4; ++ct) {
        int colg = col0 + wc * 64 + ct * 16 + l15;
        float A_ = Ac[e * HID + colg];
        float C_ = Cc[e * HID + colg];
#pragma unroll
        for (int rt = 0; rt < 2; ++rt) {
          int rb = wr * 32 + rt * 16 + quad * 4;
#pragma unroll
          for (int r = 0; r < 4; ++r) {
            float gvw = gS[(rb + r) * 17 + e];
            float z = A_ * acc[rt][ct][r] + C_;
            float sg = 1.f / (1.f + __expf(-z));
            oacc[rt][ct][r] += gvw * z * sg;
            acc[rt][ct][r] = 0.f;
          }
        }
      }
    }
    if (t < NE * 8 - 1) writeT(buf ^ 1);
    __syncthreads();
    buf ^= 1;
  }

#pragma unroll
  for (int rt = 0; rt < 2; ++rt)
#pragma unroll
    for (int ct = 0; ct < 4; ++ct)
#pragma unroll
      for (int r = 0; r < 4; ++r)
        out[(size_t)(row0 + wr * 32 + rt * 16 + quad * 4 + r) * HID +
            col0 + wc * 64 + ct * 16 + l15] = oacc[rt][ct][r];
}

// ---------------- launch -----------------------------------------------------
extern "C" void kernel_launch(void* const* d_in, const int* in_sizes, int n_in,
                              void* d_out, int out_size, void* d_ws, size_t ws_size,
                              hipStream_t stream) {
  const float* x     = (const float*)d_in[0];
  const float* gs    = (const float*)d_in[1];
  const int*   idx   = (const int*)d_in[2];     // int32 per harness (robust fallback to int64)
  const float* W     = (const float*)d_in[3];
  const float* ebias = (const float*)d_in[4];
  const float* bnw   = (const float*)d_in[5];
  const float* bnb   = (const float*)d_in[6];
  const float* rmean = (const float*)d_in[7];
  const float* rvar  = (const float*)d_in[8];
  const float* gw    = (const float*)d_in[9];
  const float* lA    = (const float*)d_in[10];
  const float* lB    = (const float*)d_in[11];
  float* out = (float*)d_out;

  char* ws = (char*)d_ws;
  unsigned short* WT = (unsigned short*)ws;                    // 16,777,216 B
  unsigned short* xg = (unsigned short*)(ws + 16777216);       //  2,097,152 B
  float* g   = (float*)(ws + 18874368);                        //    131,072 B
  float* Acf = (float*)(ws + 19005440);                        //     65,536 B
  float* Ccf = (float*)(ws + 19070976);                        //     65,536 B

  prep_coef<<<dim3(64), dim3(256), 0, stream>>>(idx, bnw, bnb, rmean, rvar, ebias, Acf, Ccf);
  prep_rows<<<dim3(BATCH / 4), dim3(256), 0, stream>>>(x, gs, gw, lA, lB, xg, g);
  prep_tw<<<dim3(2048), dim3(256), 0, stream>>>(idx, W, WT);
  moe_main<<<dim3((BATCH / BM) * (HID / BN)), dim3(256), 0, stream>>>(xg, WT, g, Acf, Ccf, out);
}

// Round 3
// 197.256 us; speedup vs baseline: 1.4368x; 1.4368x over previous
//
#include <hip/hip_runtime.h>
#include <hip/hip_bf16.h>

#define BATCH 2048
#define IN_DIM 512
#define HID 1024
#define NE 16
#define EPSV 1e-5f

typedef __bf16 bf16x8 __attribute__((ext_vector_type(8)));
typedef float floatx4 __attribute__((ext_vector_type(4)));
typedef unsigned short ushort8 __attribute__((ext_vector_type(8)));

__device__ __forceinline__ unsigned short f2bf(float f) {
  unsigned int u = __builtin_bit_cast(unsigned int, f);
  u += 0x7FFFu + ((u >> 16) & 1u);   // RNE
  return (unsigned short)(u >> 16);
}

__device__ __forceinline__ int get_expert(const int* __restrict__ idx, int e) {
  bool is64 = (idx[1] == 0) && (idx[3] == 0);
  return is64 ? (int)((const long long*)idx)[e] : idx[e];
}

// async 16B/lane global->LDS (DMA, no VGPR roundtrip). LDS dest is
// wave-uniform base + lane*16; global addr is per-lane.
__device__ __forceinline__ void gld16(void* lds, const void* g) {
  __builtin_amdgcn_global_load_lds(
      (const __attribute__((address_space(1))) void*)g,
      (__attribute__((address_space(3))) void*)lds, 16, 0, 0);
}

// ---------------- zero d_out (it is poisoned 0xAA before every call) ---------
__global__ __launch_bounds__(256) void zero_out(float* __restrict__ out) {
  int t = blockIdx.x * 256 + threadIdx.x;
  ((float4*)out)[t] = float4{0.f, 0.f, 0.f, 0.f};
}

// ---------------- prep 1: BN coefficients (gathered by expert_indices) -------
__global__ __launch_bounds__(256) void prep_coef(
    const int* __restrict__ idx, const float* __restrict__ bnw,
    const float* __restrict__ bnb, const float* __restrict__ rmean,
    const float* __restrict__ rvar, const float* __restrict__ ebias,
    float* __restrict__ Ac, float* __restrict__ Cc) {
  int t = blockIdx.x * 256 + threadIdx.x;      // 16384 = NE*HID
  int e = t >> 10, h = t & 1023;
  int ie = get_expert(idx, e);
  size_t o = (size_t)ie * HID + h;
  float scale = bnw[o] * rsqrtf(rvar[o] + EPSV);
  Ac[t] = scale;
  Cc[t] = (ebias[o] - rmean[o]) * scale + bnb[o];
}

// ---------------- prep 2: LoRA gate (xg bf16) + softmax gate g ---------------
__global__ __launch_bounds__(256) void prep_rows(
    const float* __restrict__ x, const float* __restrict__ gs,
    const float* __restrict__ gw, const float* __restrict__ lA,
    const float* __restrict__ lB,
    unsigned short* __restrict__ xg, float* __restrict__ g) {
  int lane = threadIdx.x & 63;
  int wid = threadIdx.x >> 6;
  int b = blockIdx.x * 4 + wid;                // one wave per row
  const float* xrow = x + (size_t)b * IN_DIM;
  const float* grow = gs + (size_t)b * IN_DIM;
  int d0 = lane * 8;

  float4 xa = *(const float4*)(xrow + d0);
  float4 xb = *(const float4*)(xrow + d0 + 4);
  float xv[8] = {xa.x, xa.y, xa.z, xa.w, xb.x, xb.y, xb.z, xb.w};
  float4 ga = *(const float4*)(grow + d0);
  float4 gb = *(const float4*)(grow + d0 + 4);
  float gv[8] = {ga.x, ga.y, ga.z, ga.w, gb.x, gb.y, gb.z, gb.w};

  float u0 = 0.f, u1 = 0.f;
#pragma unroll
  for (int j = 0; j < 8; ++j) {
    float2 a2 = *(const float2*)(lA + (size_t)(d0 + j) * 2);
    u0 += xv[j] * a2.x;
    u1 += xv[j] * a2.y;
  }
#pragma unroll
  for (int off = 1; off < 64; off <<= 1) {
    u0 += __shfl_xor(u0, off);
    u1 += __shfl_xor(u1, off);
  }

  float ge[16];
#pragma unroll
  for (int e = 0; e < 16; ++e) ge[e] = 0.f;
#pragma unroll
  for (int j = 0; j < 8; ++j) {
    float q = gv[j];
    const float4* gwr = (const float4*)(gw + (size_t)(d0 + j) * NE);
    float4 w0 = gwr[0], w1 = gwr[1], w2 = gwr[2], w3 = gwr[3];
    ge[0] += q * w0.x; ge[1] += q * w0.y; ge[2] += q * w0.z; ge[3] += q * w0.w;
    ge[4] += q * w1.x; ge[5] += q * w1.y; ge[6] += q * w1.z; ge[7] += q * w1.w;
    ge[8] += q * w2.x; ge[9] += q * w2.y; ge[10] += q * w2.z; ge[11] += q * w2.w;
    ge[12] += q * w3.x; ge[13] += q * w3.y; ge[14] += q * w3.z; ge[15] += q * w3.w;
  }
#pragma unroll
  for (int off = 1; off < 64; off <<= 1) {
#pragma unroll
    for (int e = 0; e < 16; ++e) ge[e] += __shfl_xor(ge[e], off);
  }
  float m = ge[0];
#pragma unroll
  for (int e = 1; e < 16; ++e) m = fmaxf(m, ge[e]);
  float p[16], s = 0.f;
#pragma unroll
  for (int e = 0; e < 16; ++e) { p[e] = __expf(ge[e] - m); s += p[e]; }
  float inv = 1.f / s;
  if (lane == 0) {
    float* gout = g + (size_t)b * NE;
#pragma unroll
    for (int e = 0; e < 16; ++e) gout[e] = p[e] * inv;
  }

  ushort8 ov;
#pragma unroll
  for (int j = 0; j < 8; ++j) {
    float t = u0 * lB[d0 + j] + u1 * lB[IN_DIM + d0 + j];
    float sg = 1.f / (1.f + __expf(-t));
    ov[j] = f2bf(xv[j] * sg);
  }
  *(ushort8*)(xg + (size_t)b * IN_DIM + d0) = ov;
}

// ---------------- prep 3: W[e][k][h] fp32 -> WbfT[e][h][k] bf16 --------------
__global__ __launch_bounds__(256) void prep_tw(
    const int* __restrict__ idx, const float* __restrict__ W,
    unsigned short* __restrict__ WT) {
  int bid = blockIdx.x;                // 16 * 8 * 16 = 2048 blocks
  int e = bid >> 7;
  int kt = (bid >> 4) & 7;
  int ht = bid & 15;
  int ie = get_expert(idx, e);
  int k0 = kt * 64, h0 = ht * 64;
  __shared__ float tile[64][65];
  const float* Wp = W + (size_t)ie * IN_DIM * HID;
#pragma unroll
  for (int i = 0; i < 4; ++i) {
    int id = threadIdx.x + i * 256;    // 0..1023
    int k = id >> 4, c = (id & 15) * 4;
    float4 v = *(const float4*)(Wp + (size_t)(k0 + k) * HID + h0 + c);
    tile[k][c] = v.x; tile[k][c + 1] = v.y; tile[k][c + 2] = v.z; tile[k][c + 3] = v.w;
  }
  __syncthreads();
#pragma unroll
  for (int i = 0; i < 2; ++i) {
    int id = threadIdx.x + i * 256;    // 0..511
    int h = id >> 3, kc = (id & 7) * 8;
    ushort8 o;
#pragma unroll
    for (int j = 0; j < 8; ++j) o[j] = f2bf(tile[kc + j][h]);
    *(ushort8*)(WT + ((size_t)e * HID + h0 + h) * IN_DIM + k0 + kc) = o;
  }
}

// ---------------- main: 128x128 tile, 4 experts/block, global_load_lds -------
#define BM 128
#define BN 128
#define BK 32
#define EPB 4     // experts per block (4-way split over 16)

__global__ __launch_bounds__(256, 2) void moe_main(
    const unsigned short* __restrict__ xg, const unsigned short* __restrict__ WT,
    const float* __restrict__ g, const float* __restrict__ Ac,
    const float* __restrict__ Cc, float* __restrict__ out) {
  // Unpadded 64B rows (BK=32 bf16) — required contiguous for global_load_lds;
  // fragment-read banks = 4*((l15&1)*4 + quad): all 8 groups hit, conflict-free.
  __shared__ __align__(16) unsigned short As[2][BM * BK];
  __shared__ __align__(16) unsigned short Bs[2][BN * BK];
  __shared__ float gS[BM][EPB];

  int tid = threadIdx.x;
  int lane = tid & 63, w = tid >> 6;
  int wr = w >> 1, wc = w & 1;          // wave tile 64x64
  int l15 = lane & 15, quad = lane >> 4;

  int bid = blockIdx.x;                 // p in top bits (time-separate same-tile
  int p = bid >> 7;                     // atomics), colb in low 3 (XCD L2 reuse)
  int rowb = (bid >> 3) & 15, colb = bid & 7;
  int row0 = rowb * BM, col0 = colb * BN;
  int e0 = p * EPB;

  for (int i = tid; i < BM * EPB; i += 256) {
    int r = i >> 2, e = i & 3;
    gS[r][e] = g[(size_t)(row0 + r) * NE + e0 + e];
  }

  // per-lane global source offsets for the DMA (16 rows per instruction)
  int dr = lane >> 2, dk = (lane & 3) * 8;
  const unsigned short* gA = xg + (size_t)(row0 + w * 32 + dr) * IN_DIM + dk;
  const unsigned short* gB0 = WT + ((size_t)e0 * HID + col0 + w * 32 + dr) * IN_DIM + dk;

  auto dma = [&](int t, int buf) {
    int e = t >> 4, k0 = (t & 15) * BK;
    const unsigned short* a = gA + k0;
    const unsigned short* b = gB0 + (size_t)e * HID * IN_DIM + k0;
#pragma unroll
    for (int j = 0; j < 2; ++j) {
      gld16(&As[buf][(w * 32 + j * 16) * BK], a + (size_t)j * 16 * IN_DIM);
      gld16(&Bs[buf][(w * 32 + j * 16) * BK], b + (size_t)j * 16 * IN_DIM);
    }
  };

  floatx4 acc[4][4], oacc[4][4];
#pragma unroll
  for (int rt = 0; rt < 4; ++rt)
#pragma unroll
    for (int ct = 0; ct < 4; ++ct)
#pragma unroll
      for (int r = 0; r < 4; ++r) { acc[rt][ct][r] = 0.f; oacc[rt][ct][r] = 0.f; }

  dma(0, 0);
  __syncthreads();
  int buf = 0;
  for (int t = 0; t < EPB * 16; ++t) {
    if (t < EPB * 16 - 1) dma(t + 1, buf ^ 1);
    bf16x8 af[4], bf[4];
#pragma unroll
    for (int rt = 0; rt < 4; ++rt)
      af[rt] = *(const bf16x8*)&As[buf][(wr * 64 + rt * 16 + l15) * BK + quad * 8];
#pragma unroll
    for (int ct = 0; ct < 4; ++ct)
      bf[ct] = *(const bf16x8*)&Bs[buf][(wc * 64 + ct * 16 + l15) * BK + quad * 8];
#pragma unroll
    for (int rt = 0; rt < 4; ++rt)
#pragma unroll
      for (int ct = 0; ct < 4; ++ct)
        acc[rt][ct] = __builtin_amdgcn_mfma_f32_16x16x32_bf16(af[rt], bf[ct], acc[rt][ct], 0, 0, 0);
    if ((t & 15) == 15) {               // expert epilogue: BN + SiLU + gated acc
      int e = t >> 4;
#pragma unroll
      for (int ct = 0; ct < 4; ++ct) {
        int colg = col0 + wc * 64 + ct * 16 + l15;
        float A_ = Ac[(e0 + e) * HID + colg];
        float C_ = Cc[(e0 + e) * HID + colg];
#pragma unroll
        for (int rt = 0; rt < 4; ++rt) {
          int rb = wr * 64 + rt * 16 + quad * 4;
#pragma unroll
          for (int r = 0; r < 4; ++r) {
            float gvw = gS[rb + r][e];
            float z = A_ * acc[rt][ct][r] + C_;
            float sg = 1.f / (1.f + __expf(-z));
            oacc[rt][ct][r] += gvw * z * sg;
            acc[rt][ct][r] = 0.f;
          }
        }
      }
    }
    __syncthreads();
    buf ^= 1;
  }

  // combine the 4 expert-splits: device-scope fp32 atomics into zeroed out
#pragma unroll
  for (int rt = 0; rt < 4; ++rt)
#pragma unroll
    for (int ct = 0; ct < 4; ++ct)
#pragma unroll
      for (int r = 0; r < 4; ++r)
        atomicAdd(&out[(size_t)(row0 + wr * 64 + rt * 16 + quad * 4 + r) * HID +
                       col0 + wc * 64 + ct * 16 + l15], oacc[rt][ct][r]);
}

// ---------------- launch -----------------------------------------------------
extern "C" void kernel_launch(void* const* d_in, const int* in_sizes, int n_in,
                              void* d_out, int out_size, void* d_ws, size_t ws_size,
                              hipStream_t stream) {
  const float* x     = (const float*)d_in[0];
  const float* gs    = (const float*)d_in[1];
  const int*   idx   = (const int*)d_in[2];
  const float* W     = (const float*)d_in[3];
  const float* ebias = (const float*)d_in[4];
  const float* bnw   = (const float*)d_in[5];
  const float* bnb   = (const float*)d_in[6];
  const float* rmean = (const float*)d_in[7];
  const float* rvar  = (const float*)d_in[8];
  const float* gw    = (const float*)d_in[9];
  const float* lA    = (const float*)d_in[10];
  const float* lB    = (const float*)d_in[11];
  float* out = (float*)d_out;

  char* ws = (char*)d_ws;
  unsigned short* WT = (unsigned short*)ws;                    // 16,777,216 B
  unsigned short* xg = (unsigned short*)(ws + 16777216);       //  2,097,152 B
  float* g   = (float*)(ws + 18874368);                        //    131,072 B
  float* Acf = (float*)(ws + 19005440);                        //     65,536 B
  float* Ccf = (float*)(ws + 19070976);                        //     65,536 B

  zero_out<<<dim3(BATCH * HID / 1024), dim3(256), 0, stream>>>(out);
  prep_coef<<<dim3(64), dim3(256), 0, stream>>>(idx, bnw, bnb, rmean, rvar, ebias, Acf, Ccf);
  prep_rows<<<dim3(BATCH / 4), dim3(256), 0, stream>>>(x, gs, gw, lA, lB, xg, g);
  prep_tw<<<dim3(2048), dim3(256), 0, stream>>>(idx, W, WT);
  moe_main<<<dim3((BATCH / BM) * (HID / BN) * (NE / EPB)), dim3(256), 0, stream>>>(
      xg, WT, g, Acf, Ccf, out);
}

// Round 4
// 179.063 us; speedup vs baseline: 1.5828x; 1.1016x over previous
//
#include <hip/hip_runtime.h>
#include <hip/hip_bf16.h>

#define BATCH 2048
#define IN_DIM 512
#define HID 1024
#define NE 16
#define EPSV 1e-5f

typedef __bf16 bf16x8 __attribute__((ext_vector_type(8)));
typedef float floatx4 __attribute__((ext_vector_type(4)));
typedef unsigned short ushort8 __attribute__((ext_vector_type(8)));

__device__ __forceinline__ unsigned short f2bf(float f) {
  unsigned int u = __builtin_bit_cast(unsigned int, f);
  u += 0x7FFFu + ((u >> 16) & 1u);   // RNE
  return (unsigned short)(u >> 16);
}

__device__ __forceinline__ int get_expert(const int* __restrict__ idx, int e) {
  bool is64 = (idx[1] == 0) && (idx[3] == 0);
  return is64 ? (int)((const long long*)idx)[e] : idx[e];
}

__device__ __forceinline__ void gld16(void* lds, const void* g) {
  __builtin_amdgcn_global_load_lds(
      (const __attribute__((address_space(1))) void*)g,
      (__attribute__((address_space(3))) void*)lds, 16, 0, 0);
}

// ============ fused prep: [0,2048) W-transpose | [2048,2560) rows | [2560,2624) coef
__global__ __launch_bounds__(256) void prep_all(
    const int* __restrict__ idx, const float* __restrict__ W,
    unsigned short* __restrict__ WT,
    const float* __restrict__ x, const float* __restrict__ gs,
    const float* __restrict__ gw, const float* __restrict__ lA,
    const float* __restrict__ lB,
    unsigned short* __restrict__ xg, float* __restrict__ g,
    const float* __restrict__ bnw, const float* __restrict__ bnb,
    const float* __restrict__ rmean, const float* __restrict__ rvar,
    const float* __restrict__ ebias,
    float* __restrict__ Ac, float* __restrict__ Cc) {
  int bid = blockIdx.x;
  if (bid < 2048) {
    // ---- W[e][k][h] fp32 -> WT[e][h][k] bf16, 64x64 tiles ----
    int e = bid >> 7, kt = (bid >> 4) & 7, ht = bid & 15;
    int ie = get_expert(idx, e);
    int k0 = kt * 64, h0 = ht * 64;
    __shared__ float tile[64][65];
    const float* Wp = W + (size_t)ie * IN_DIM * HID;
#pragma unroll
    for (int i = 0; i < 4; ++i) {
      int id = threadIdx.x + i * 256;
      int k = id >> 4, c = (id & 15) * 4;
      float4 v = *(const float4*)(Wp + (size_t)(k0 + k) * HID + h0 + c);
      tile[k][c] = v.x; tile[k][c + 1] = v.y; tile[k][c + 2] = v.z; tile[k][c + 3] = v.w;
    }
    __syncthreads();
#pragma unroll
    for (int i = 0; i < 2; ++i) {
      int id = threadIdx.x + i * 256;
      int h = id >> 3, kc = (id & 7) * 8;
      ushort8 o;
#pragma unroll
      for (int j = 0; j < 8; ++j) o[j] = f2bf(tile[kc + j][h]);
      *(ushort8*)(WT + ((size_t)e * HID + h0 + h) * IN_DIM + k0 + kc) = o;
    }
  } else if (bid < 2560) {
    // ---- LoRA gate xg (bf16) + softmax gate g, one wave per row ----
    int lane = threadIdx.x & 63;
    int b = (bid - 2048) * 4 + (threadIdx.x >> 6);
    const float* xrow = x + (size_t)b * IN_DIM;
    const float* grow = gs + (size_t)b * IN_DIM;
    int d0 = lane * 8;
    float4 xa = *(const float4*)(xrow + d0);
    float4 xb = *(const float4*)(xrow + d0 + 4);
    float xv[8] = {xa.x, xa.y, xa.z, xa.w, xb.x, xb.y, xb.z, xb.w};
    float4 ga = *(const float4*)(grow + d0);
    float4 gb = *(const float4*)(grow + d0 + 4);
    float gv[8] = {ga.x, ga.y, ga.z, ga.w, gb.x, gb.y, gb.z, gb.w};

    float u0 = 0.f, u1 = 0.f;
#pragma unroll
    for (int j = 0; j < 8; ++j) {
      float2 a2 = *(const float2*)(lA + (size_t)(d0 + j) * 2);
      u0 += xv[j] * a2.x;
      u1 += xv[j] * a2.y;
    }
#pragma unroll
    for (int off = 1; off < 64; off <<= 1) {
      u0 += __shfl_xor(u0, off);
      u1 += __shfl_xor(u1, off);
    }
    float ge[16];
#pragma unroll
    for (int e = 0; e < 16; ++e) ge[e] = 0.f;
#pragma unroll
    for (int j = 0; j < 8; ++j) {
      float q = gv[j];
      const float4* gwr = (const float4*)(gw + (size_t)(d0 + j) * NE);
      float4 w0 = gwr[0], w1 = gwr[1], w2 = gwr[2], w3 = gwr[3];
      ge[0] += q * w0.x; ge[1] += q * w0.y; ge[2] += q * w0.z; ge[3] += q * w0.w;
      ge[4] += q * w1.x; ge[5] += q * w1.y; ge[6] += q * w1.z; ge[7] += q * w1.w;
      ge[8] += q * w2.x; ge[9] += q * w2.y; ge[10] += q * w2.z; ge[11] += q * w2.w;
      ge[12] += q * w3.x; ge[13] += q * w3.y; ge[14] += q * w3.z; ge[15] += q * w3.w;
    }
#pragma unroll
    for (int off = 1; off < 64; off <<= 1) {
#pragma unroll
      for (int e = 0; e < 16; ++e) ge[e] += __shfl_xor(ge[e], off);
    }
    float m = ge[0];
#pragma unroll
    for (int e = 1; e < 16; ++e) m = fmaxf(m, ge[e]);
    float p[16], s = 0.f;
#pragma unroll
    for (int e = 0; e < 16; ++e) { p[e] = __expf(ge[e] - m); s += p[e]; }
    float inv = 1.f / s;
    if (lane == 0) {
      float* gout = g + (size_t)b * NE;
#pragma unroll
      for (int e = 0; e < 16; ++e) gout[e] = p[e] * inv;
    }
    ushort8 ov;
#pragma unroll
    for (int j = 0; j < 8; ++j) {
      float t = u0 * lB[d0 + j] + u1 * lB[IN_DIM + d0 + j];
      float sg = 1.f / (1.f + __expf(-t));
      ov[j] = f2bf(xv[j] * sg);
    }
    *(ushort8*)(xg + (size_t)b * IN_DIM + d0) = ov;
  } else {
    // ---- BN affine coefficients ----
    int t = (bid - 2560) * 256 + threadIdx.x;  // 16384 = NE*HID
    int e = t >> 10, h = t & 1023;
    int ie = get_expert(idx, e);
    size_t o = (size_t)ie * HID + h;
    float scale = bnw[o] * rsqrtf(rvar[o] + EPSV);
    Ac[t] = scale;
    Cc[t] = (ebias[o] - rmean[o]) * scale + bnb[o];
  }
}

// ============ zero d_out (atomic fallback path only) ============
__global__ __launch_bounds__(256) void zero_out(float* __restrict__ out) {
  int t = blockIdx.x * 256 + threadIdx.x;
  ((float4*)out)[t] = float4{0.f, 0.f, 0.f, 0.f};
}

// ============ split-K combine: out = s0+s1+s2+s3 ============
__global__ __launch_bounds__(256) void reduce4(const float* __restrict__ sws,
                                               float* __restrict__ out) {
  int t = blockIdx.x * 256 + threadIdx.x;     // float4 index, 2048 blocks
  const float4* s0 = (const float4*)sws;
  const float4* s1 = s0 + (BATCH * HID / 4);
  const float4* s2 = s1 + (BATCH * HID / 4);
  const float4* s3 = s2 + (BATCH * HID / 4);
  float4 a = s0[t], b = s1[t], c = s2[t], d = s3[t];
  ((float4*)out)[t] = float4{a.x + b.x + c.x + d.x, a.y + b.y + c.y + d.y,
                             a.z + b.z + c.z + d.z, a.w + b.w + c.w + d.w};
}

// ============ main: 128x128 tile, BK=64 (two 32-k slices), dbuf, 1 barrier/iter
#define BM 128
#define BN 128
#define KS 32     // k-slice (64B LDS rows -> conflict-free fragment reads)
#define EPB 4     // experts per block (4-way split-K over 16 experts)

__global__ __launch_bounds__(256, 2) void moe_main(
    const unsigned short* __restrict__ xg, const unsigned short* __restrict__ WT,
    const float* __restrict__ g, const float* __restrict__ Ac,
    const float* __restrict__ Cc, float* __restrict__ splitws,
    float* __restrict__ out, int use_split) {
  // [buf][kslice][row*KS] — 64B rows, contiguous per gld16 (wave-uniform base),
  // fragment read banks = (l15&1)*16 + quad*4 -> 8 lanes per 4-bank group = optimal.
  __shared__ __align__(16) unsigned short As[2][2][BM * KS];
  __shared__ __align__(16) unsigned short Bs[2][2][BN * KS];
  __shared__ float gS[BM][EPB];

  int tid = threadIdx.x;
  int lane = tid & 63, w = tid >> 6;
  int wr = w >> 1, wc = w & 1;          // wave tile 64x64
  int l15 = lane & 15, quad = lane >> 4;

  int bid = blockIdx.x;                 // p in top bits, colb in low 3 (XCD L2)
  int p = bid >> 7;
  int rowb = (bid >> 3) & 15, colb = bid & 7;
  int row0 = rowb * BM, col0 = colb * BN;
  int e0 = p * EPB;

  for (int i = tid; i < BM * EPB; i += 256) {
    int r = i >> 2, e = i & 3;
    gS[r][e] = g[(size_t)(row0 + r) * NE + e0 + e];
  }

  // DMA source lanes: 16 rows x 64B per instruction
  int dr = lane >> 2, dk = (lane & 3) * 8;
  const unsigned short* gA = xg + (size_t)(row0 + w * 32 + dr) * IN_DIM + dk;
  const unsigned short* gB = WT + ((size_t)e0 * HID + col0 + w * 32 + dr) * IN_DIM + dk;

  auto dma = [&](int t, int buf) {      // t in [0,32): e = t>>3, 64-k chunk s = t&7
    int e = t >> 3, s = t & 7;
    size_t aoff = (size_t)s * 64;
    size_t boff = (size_t)e * HID * IN_DIM + s * 64;
#pragma unroll
    for (int kk = 0; kk < 2; ++kk) {
#pragma unroll
      for (int j = 0; j < 2; ++j) {
        gld16(&As[buf][kk][(w * 32 + j * 16) * KS],
              gA + aoff + kk * KS + (size_t)j * 16 * IN_DIM);
        gld16(&Bs[buf][kk][(w * 32 + j * 16) * KS],
              gB + boff + kk * KS + (size_t)j * 16 * IN_DIM);
      }
    }
  };

  floatx4 acc[4][4], oacc[4][4];
#pragma unroll
  for (int rt = 0; rt < 4; ++rt)
#pragma unroll
    for (int ct = 0; ct < 4; ++ct)
#pragma unroll
      for (int r = 0; r < 4; ++r) { acc[rt][ct][r] = 0.f; oacc[rt][ct][r] = 0.f; }

  dma(0, 0);
  __syncthreads();
  int buf = 0;
  for (int t = 0; t < 32; ++t) {
    if (t < 31) dma(t + 1, buf ^ 1);
#pragma unroll
    for (int kk = 0; kk < 2; ++kk) {
      bf16x8 af[4], bfv[4];
#pragma unroll
      for (int rt = 0; rt < 4; ++rt)
        af[rt] = *(const bf16x8*)&As[buf][kk][(wr * 64 + rt * 16 + l15) * KS + quad * 8];
#pragma unroll
      for (int ct = 0; ct < 4; ++ct)
        bfv[ct] = *(const bf16x8*)&Bs[buf][kk][(wc * 64 + ct * 16 + l15) * KS + quad * 8];
#pragma unroll
      for (int rt = 0; rt < 4; ++rt)
#pragma unroll
        for (int ct = 0; ct < 4; ++ct)
          acc[rt][ct] = __builtin_amdgcn_mfma_f32_16x16x32_bf16(af[rt], bfv[ct], acc[rt][ct], 0, 0, 0);
    }
    if ((t & 7) == 7) {                 // expert epilogue: BN + SiLU + gated acc
      int e = t >> 3;
#pragma unroll
      for (int ct = 0; ct < 4; ++ct) {
        int colg = col0 + wc * 64 + ct * 16 + l15;
        float A_ = Ac[(e0 + e) * HID + colg];
        float C_ = Cc[(e0 + e) * HID + colg];
#pragma unroll
        for (int rt = 0; rt < 4; ++rt) {
          int rb = wr * 64 + rt * 16 + quad * 4;
#pragma unroll
          for (int r = 0; r < 4; ++r) {
            float gvw = gS[rb + r][e];
            float z = A_ * acc[rt][ct][r] + C_;
            float sg = 1.f / (1.f + __expf(-z));
            oacc[rt][ct][r] += gvw * z * sg;
            acc[rt][ct][r] = 0.f;
          }
        }
      }
    }
    __syncthreads();
    buf ^= 1;
  }

  if (use_split) {
    float* sout = splitws + (size_t)p * BATCH * HID;
#pragma unroll
    for (int rt = 0; rt < 4; ++rt)
#pragma unroll
      for (int ct = 0; ct < 4; ++ct)
#pragma unroll
        for (int r = 0; r < 4; ++r)
          sout[(size_t)(row0 + wr * 64 + rt * 16 + quad * 4 + r) * HID +
               col0 + wc * 64 + ct * 16 + l15] = oacc[rt][ct][r];
  } else {
#pragma unroll
    for (int rt = 0; rt < 4; ++rt)
#pragma unroll
      for (int ct = 0; ct < 4; ++ct)
#pragma unroll
        for (int r = 0; r < 4; ++r)
          atomicAdd(&out[(size_t)(row0 + wr * 64 + rt * 16 + quad * 4 + r) * HID +
                         col0 + wc * 64 + ct * 16 + l15], oacc[rt][ct][r]);
  }
}

// ============ launch ============
extern "C" void kernel_launch(void* const* d_in, const int* in_sizes, int n_in,
                              void* d_out, int out_size, void* d_ws, size_t ws_size,
                              hipStream_t stream) {
  const float* x     = (const float*)d_in[0];
  const float* gs    = (const float*)d_in[1];
  const int*   idx   = (const int*)d_in[2];
  const float* W     = (const float*)d_in[3];
  const float* ebias = (const float*)d_in[4];
  const float* bnw   = (const float*)d_in[5];
  const float* bnb   = (const float*)d_in[6];
  const float* rmean = (const float*)d_in[7];
  const float* rvar  = (const float*)d_in[8];
  const float* gw    = (const float*)d_in[9];
  const float* lA    = (const float*)d_in[10];
  const float* lB    = (const float*)d_in[11];
  float* out = (float*)d_out;

  char* ws = (char*)d_ws;
  unsigned short* WT = (unsigned short*)ws;                    // 16,777,216 B
  unsigned short* xg = (unsigned short*)(ws + 16777216);       //  2,097,152 B
  float* g    = (float*)(ws + 18874368);                       //    131,072 B
  float* Acf  = (float*)(ws + 19005440);                       //     65,536 B
  float* Ccf  = (float*)(ws + 19070976);                       //     65,536 B
  float* sws  = (float*)(ws + 19136512);                       // 33,554,432 B (split-K)
  int use_split = (ws_size >= 19136512 + 4ull * BATCH * HID * 4) ? 1 : 0;

  prep_all<<<dim3(2624), dim3(256), 0, stream>>>(
      idx, W, WT, x, gs, gw, lA, lB, xg, g, bnw, bnb, rmean, rvar, ebias, Acf, Ccf);
  if (!use_split)
    zero_out<<<dim3(BATCH * HID / 1024), dim3(256), 0, stream>>>(out);
  moe_main<<<dim3((BATCH / BM) * (HID / BN) * (NE / EPB)), dim3(256), 0, stream>>>(
      xg, WT, g, Acf, Ccf, sws, out, use_split);
  if (use_split)
    reduce4<<<dim3(BATCH * HID / 1024), dim3(256), 0, stream>>>(sws, out);
}